// Round 5
// baseline (261.958 us; speedup 1.0000x reference)
//
#include <hip/hip_runtime.h>

#define OUT_W 1024
#define OUT_H 1024
#define BOXES_PER_BLOCK 16

typedef float f32x4 __attribute__((ext_vector_type(4)));

// 2048 blocks x 256 threads; each block handles 16 consecutive boxes.
// Phase 1 prefetches all 16 (center, wh) pairs (uniform addresses -> scalar
// loads, one lgkmcnt wait). Phase 2 is a fully-unrolled stream of
// compute + 2 dwordx4 stores per box -> 32 independent stores per wave in
// flight, mimicking the fill kernel's store-streaming shape that reaches
// 6.6 TB/s at 10% occupancy. Plain stores (through L2) -- the R3 experiment
// showed nontemporal stores regress ~20%.
__global__ __launch_bounds__(256)
void gv_kernel(const float* __restrict__ center,
               const float* __restrict__ wh,
               float* __restrict__ out_x,
               float* __restrict__ out_y)
{
    const int t   = threadIdx.x;
    const int bn0 = blockIdx.x * BOXES_PER_BLOCK;
    const float pf = (float)(t * 4);

    float2 c[BOXES_PER_BLOCK], w[BOXES_PER_BLOCK];
#pragma unroll
    for (int k = 0; k < BOXES_PER_BLOCK; ++k) {
        c[k] = reinterpret_cast<const float2*>(center)[bn0 + k];
        w[k] = reinterpret_cast<const float2*>(wh)[bn0 + k];
    }

#pragma unroll
    for (int k = 0; k < BOXES_PER_BLOCK; ++k) {
        const float cx = c[k].x, cy = c[k].y, Wb = w[k].x, Hb = w[k].y;

        // ks = floor(W/2)*2 - 1 ; r = floor((ks-1)/2) ; sigma = floor(r/3)
        const float ksw = floorf(Wb * 0.5f) * 2.0f - 1.0f;
        const float rw  = floorf((ksw - 1.0f) * 0.5f);
        const float sw  = floorf(rw / 3.0f);
        const float ksh = floorf(Hb * 0.5f) * 2.0f - 1.0f;
        const float rh  = floorf((ksh - 1.0f) * 0.5f);
        const float sh  = floorf(rh / 3.0f);

        const bool zero_box = ((cx + cy) + (Wb + Hb)) == 0.0f;

        // SCALE = 1.0 ; trunc toward zero (astype(int32))
        const float x = truncf(cx);
        const float y = truncf(cy);

        const float ul0 = x - rw;
        const float ul1 = y - rh;
        const float br0 = x + rw + 1.0f;
        const float br1 = y + rh + 1.0f;

        const bool in_ul = (ul0 >= 0.0f) && (ul0 <= (float)OUT_W) &&
                           (ul1 >= 0.0f) && (ul1 <= (float)OUT_H);
        const bool in_br = (br0 >= 0.0f) && (br0 <= (float)OUT_W) &&
                           (br1 >= 0.0f) && (br1 <= (float)OUT_H);
        const bool active = (!zero_box) && (sw != 0.0f) && (sh != 0.0f) && (in_ul || in_br);

        const float ssw = (sw == 0.0f) ? 1.0f : sw;
        const float ssh = (sh == 0.0f) ? 1.0f : sh;
        const float iw  = -1.0f / (2.0f * ssw * ssw);
        const float ih  = -1.0f / (2.0f * ssh * ssh);

        f32x4 rx, ry;
#pragma unroll
        for (int i = 0; i < 4; ++i) {
            const float p  = pf + (float)i;
            const float dx = p - x;
            const float dy = p - y;
            const bool mx = active && (p >= ul0) && (p < br0);
            const bool my = active && (p >= ul1) && (p < br1);
            rx[i] = mx ? __expf(dx * dx * iw) : 0.0f;
            ry[i] = my ? __expf(dy * dy * ih) : 0.0f;
        }

        const size_t row = (size_t)(bn0 + k) * (OUT_W / 4) + t;
        reinterpret_cast<f32x4*>(out_x)[row] = rx;
        reinterpret_cast<f32x4*>(out_y)[row] = ry;
    }
}

extern "C" void kernel_launch(void* const* d_in, const int* in_sizes, int n_in,
                              void* d_out, int out_size, void* d_ws, size_t ws_size,
                              hipStream_t stream) {
    const float* center = (const float*)d_in[0];  // [B,N,2]
    const float* wh     = (const float*)d_in[1];  // [B,N,2]
    float* out = (float*)d_out;                   // vector_x ++ vector_y, fp32

    const int BN = in_sizes[0] / 2;               // B*N = 32768 (divisible by 16)
    float* out_x = out;
    float* out_y = out + (size_t)BN * OUT_W;

    const int grid = BN / BOXES_PER_BLOCK;
    gv_kernel<<<dim3(grid), dim3(256), 0, stream>>>(center, wh, out_x, out_y);
}